// Round 1
// baseline (7853.820 us; speedup 1.0000x reference)
//
#include <hip/hip_runtime.h>
#include <hip/hip_bf16.h>
#include <math.h>

// ---------------------------------------------------------------------------
// DepthlessTransformer forward, fp32 correctness-first implementation.
// D=512, H=8, DH=64, DI=512, L=6, NEX=6, FFI=1365, V=32000, B=2, N=192
// Key optimization vs naive reference: pooled-attention context kv is
// computed ONCE per message entry and cached (78 entries total), instead of
// recomputed (and L-duplicated) every exchange.
// ---------------------------------------------------------------------------

#define EPSV 1.1920929e-07f

// ======================= generic batched GEMM: C = A * W^T (+bias) =========
// A: [M, K] row-major (per batch, stride aStr)
// W: [N, K] row-major (per batch, stride wStr)   C: [M, N] (stride cStr)
#define TS 64
#define KS 32
__global__ __launch_bounds__(256) void gemm_kernel(
    const float* __restrict__ A, const float* __restrict__ W,
    const float* __restrict__ bias, float* __restrict__ C,
    int M, int N, int K,
    long long aStr, long long wStr, long long bStr, long long cStr)
{
  int batch = blockIdx.z;
  A += (size_t)batch * aStr;
  W += (size_t)batch * wStr;
  C += (size_t)batch * cStr;
  if (bias) bias += (size_t)batch * bStr;
  int m0 = blockIdx.y * TS, n0 = blockIdx.x * TS;
  __shared__ float As[KS][TS + 1];
  __shared__ float Ws[KS][TS + 1];
  int t = threadIdx.x;
  int tx = t & 15, ty = t >> 4;
  float acc[4][4] = {};
  for (int k0 = 0; k0 < K; k0 += KS) {
#pragma unroll
    for (int p = 0; p < 8; ++p) {
      int idx = t + p * 256;       // 0..2047
      int kk = idx & (KS - 1);     // 0..31
      int rr = idx >> 5;           // 0..63
      float av = 0.f, wv = 0.f;
      if (k0 + kk < K) {
        if (m0 + rr < M) av = A[(size_t)(m0 + rr) * K + k0 + kk];
        if (n0 + rr < N) wv = W[(size_t)(n0 + rr) * K + k0 + kk];
      }
      As[kk][rr] = av;
      Ws[kk][rr] = wv;
    }
    __syncthreads();
#pragma unroll
    for (int kk = 0; kk < KS; ++kk) {
      float a[4], w[4];
#pragma unroll
      for (int u = 0; u < 4; ++u) { a[u] = As[kk][ty + u * 16]; w[u] = Ws[kk][tx + u * 16]; }
#pragma unroll
      for (int um = 0; um < 4; ++um)
#pragma unroll
        for (int un = 0; un < 4; ++un)
          acc[um][un] += a[um] * w[un];
    }
    __syncthreads();
  }
#pragma unroll
  for (int um = 0; um < 4; ++um) {
    int m = m0 + ty + um * 16;
    if (m >= M) continue;
#pragma unroll
    for (int un = 0; un < 4; ++un) {
      int n = n0 + tx + un * 16;
      if (n >= N) continue;
      float v = acc[um][un];
      if (bias) v += bias[n];
      C[(size_t)m * N + n] = v;
    }
  }
}

// ======================= rmsnorm over dim 512 ==============================
// rows_per_w: weight row = r / rows_per_w (for per-l weights)
__global__ __launch_bounds__(256) void rmsnorm_kernel(
    const float* __restrict__ x, const float* __restrict__ w,
    float* __restrict__ out, int rows_per_w)
{
  int r = blockIdx.x;
  int t = threadIdx.x;
  const float* xr = x + (size_t)r * 512;
  float a = xr[t], b = xr[t + 256];
  float ss = a * a + b * b;
  for (int off = 32; off; off >>= 1) ss += __shfl_xor(ss, off);
  __shared__ float wsum[4];
  if ((t & 63) == 0) wsum[t >> 6] = ss;
  __syncthreads();
  float tot = wsum[0] + wsum[1] + wsum[2] + wsum[3];
  float rs = rsqrtf(tot * (1.f / 512.f) + EPSV);
  const float* wr = w + (size_t)(r / rows_per_w) * 512;
  out[(size_t)r * 512 + t] = a * rs * wr[t];
  out[(size_t)r * 512 + t + 256] = b * rs * wr[t + 256];
}

// ======================= broadcast tokens -> toks[L] =======================
__global__ void bcast_kernel(const float* __restrict__ tokens, float* __restrict__ toks)
{
  size_t idx = (size_t)blockIdx.x * 256 + threadIdx.x;
  const size_t total = (size_t)6 * 2 * 192 * 512;
  if (idx >= total) return;
  toks[idx] = tokens[idx % ((size_t)2 * 192 * 512)];
}

// ======================= GEGLU activation ==================================
// z: [rows, 2730] -> act: [rows, 1365], act = sim * gelu_exact(gates)
__global__ void geglu_kernel(const float* __restrict__ z, float* __restrict__ act)
{
  int r = blockIdx.x;
  const float* zr = z + (size_t)r * 2730;
  float* ar = act + (size_t)r * 1365;
  for (int c = threadIdx.x; c < 1365; c += blockDim.x) {
    float s = zr[c], g = zr[c + 1365];
    float gl = 0.5f * g * (1.f + erff(g * 0.70710678118654752f));
    ar[c] = s * gl;
  }
}

// ======================= fused per-row block self-attention ================
// q: [12, 192, 512]; kv: [12, 192, 1024] (k cols 0..511, v cols 512..1023)
// o: [12, 192, 512].  grid (192, 8, 12), block 64.
__global__ __launch_bounds__(64) void block_attn_kernel(
    const float* __restrict__ q, const float* __restrict__ kv, float* __restrict__ o)
{
  int i = blockIdx.x, h = blockIdx.y, lb = blockIdx.z;
  int lane = threadIdx.x;
  __shared__ float qs[64];
  __shared__ float p[192];
  const float* qrow = q + ((size_t)(lb * 192 + i)) * 512 + h * 64;
  qs[lane] = qrow[lane];
  __syncthreads();
  const float* kb = kv + (size_t)lb * 192 * 1024 + h * 64;
  float s[3];
#pragma unroll
  for (int r = 0; r < 3; ++r) {
    int j = lane + r * 64;
    const float* krow = kb + (size_t)j * 1024;
    float acc = 0.f;
    for (int d = 0; d < 64; ++d) acc += qs[d] * krow[d];
    s[r] = acc;
  }
  float mx = fmaxf(fmaxf(s[0], s[1]), s[2]);
  for (int off = 32; off; off >>= 1) mx = fmaxf(mx, __shfl_xor(mx, off));
  float sum = 0.f;
#pragma unroll
  for (int r = 0; r < 3; ++r) { s[r] = expf(s[r] - mx); sum += s[r]; }
  for (int off = 32; off; off >>= 1) sum += __shfl_xor(sum, off);
  float inv = 1.f / sum;
#pragma unroll
  for (int r = 0; r < 3; ++r) p[lane + r * 64] = s[r] * inv;
  __syncthreads();
  const float* vb = kb + 512;
  float acc = 0.f;
  for (int j = 0; j < 192; ++j) acc += p[j] * vb[(size_t)j * 1024 + lane];
  o[((size_t)(lb * 192 + i)) * 512 + h * 64 + lane] = acc;
}

// ======================= fused pooled attention ============================
// Kc/Vc: [78, B=2, 192, 512] (entry e = msg*L + l, key-rmsnormed K).
// intermediate (single_q=0): q rows j*192+n (j = l*B+b), ctx batch j/6,
//   grid (192, 8, 12)
// readout (single_q=1): q is one row [512], grid (192, 8, 2), z = batch.
__global__ __launch_bounds__(64) void pooled_attn_kernel(
    const float* __restrict__ q, const float* __restrict__ Kc,
    const float* __restrict__ Vc, float* __restrict__ o, int M, int single_q)
{
  int n = blockIdx.x, h = blockIdx.y, j = blockIdx.z;
  int lane = threadIdx.x;
  int ctx_b = single_q ? j : (j / 6);
  __shared__ float qs[64];
  __shared__ float p[128];
  const float* qrow = single_q ? (q + h * 64)
                               : (q + ((size_t)(j * 192 + n)) * 512 + h * 64);
  qs[lane] = qrow[lane];
  __syncthreads();
  float s0 = -1e30f, s1 = -1e30f;
  if (lane < M) {
    const float* krow = Kc + (((size_t)lane * 2 + ctx_b) * 192 + n) * 512 + h * 64;
    float acc = 0.f;
    for (int d = 0; d < 64; ++d) acc += qs[d] * krow[d];
    s0 = acc;
  }
  int m1 = lane + 64;
  if (m1 < M) {
    const float* krow = Kc + (((size_t)m1 * 2 + ctx_b) * 192 + n) * 512 + h * 64;
    float acc = 0.f;
    for (int d = 0; d < 64; ++d) acc += qs[d] * krow[d];
    s1 = acc;
  }
  float mx = fmaxf(s0, s1);
  for (int off = 32; off; off >>= 1) mx = fmaxf(mx, __shfl_xor(mx, off));
  float e0 = (lane < M) ? expf(s0 - mx) : 0.f;
  float e1 = (m1 < M) ? expf(s1 - mx) : 0.f;
  float sum = e0 + e1;
  for (int off = 32; off; off >>= 1) sum += __shfl_xor(sum, off);
  float inv = 1.f / sum;
  p[lane] = e0 * inv;
  if (m1 < M) p[m1] = e1 * inv;
  __syncthreads();
  float acc = 0.f;
  for (int m = 0; m < M; ++m)
    acc += p[m] * Vc[(((size_t)m * 2 + ctx_b) * 192 + n) * 512 + h * 64 + lane];
  int orow = j * 192 + n;
  o[(size_t)orow * 512 + h * 64 + lane] = acc;
}

// ======================= kv-cache fill (split + per-head key rmsnorm) ======
// kvp: [T, 192, 1024] with t = g*B + b, g = local entry, b = batch.
// writes Kc/Vc entries e = base_e + g.  grid (192, T), block 128.
__global__ __launch_bounds__(128) void cache_fill_kernel(
    const float* __restrict__ kvp, const float* __restrict__ knw,
    float* __restrict__ Kc, float* __restrict__ Vc, int base_e)
{
  int n = blockIdx.x;
  int t = blockIdx.y;
  int g = t >> 1, b = t & 1;
  int e = base_e + g;
  int lane = threadIdx.x;  // 0..127, 4 cols each (512 k cols); 16 lanes/head
  const float* src = kvp + ((size_t)t * 192 + n) * 1024;
  float k4[4];
  float ss = 0.f;
#pragma unroll
  for (int u = 0; u < 4; ++u) { k4[u] = src[lane * 4 + u]; ss += k4[u] * k4[u]; }
  for (int off = 8; off; off >>= 1) ss += __shfl_xor(ss, off, 16);
  float rs = rsqrtf(ss * (1.f / 64.f) + EPSV);
  float* kd = Kc + (((size_t)e * 2 + b) * 192 + n) * 512;
  float* vd = Vc + (((size_t)e * 2 + b) * 192 + n) * 512;
#pragma unroll
  for (int u = 0; u < 4; ++u) {
    int c = lane * 4 + u;
    kd[c] = k4[u] * rs * knw[c & 63];
    vd[c] = src[512 + c];
  }
}

// ===========================================================================
extern "C" void kernel_launch(void* const* d_in, const int* in_sizes, int n_in,
                              void* d_out, int out_size, void* d_ws, size_t ws_size,
                              hipStream_t stream)
{
  const float* tokens   = (const float*)d_in[0];
  const float* attn_nw  = (const float*)d_in[1];
  const float* attn_qw  = (const float*)d_in[2];
  const float* attn_kvw = (const float*)d_in[3];
  const float* attn_ow  = (const float*)d_in[4];
  const float* ff_nw    = (const float*)d_in[5];
  const float* ff_kw    = (const float*)d_in[6];
  const float* ff_kb    = (const float*)d_in[7];
  const float* ff_vw    = (const float*)d_in[8];
  const float* ff_vb    = (const float*)d_in[9];
  const float* res_nw   = (const float*)d_in[10];
  const float* res_knw  = (const float*)d_in[11];
  const float* res_qw   = (const float*)d_in[12];
  const float* res_kvw  = (const float*)d_in[13];
  const float* res_ow   = (const float*)d_in[14];
  const float* q_ro     = (const float*)d_in[15];
  const float* ro_nw    = (const float*)d_in[16];
  const float* ro_w     = (const float*)d_in[17];
  float* out = (float*)d_out;

  // ---- workspace carve-up (floats) ----
  const size_t NEED = 56032000ull * 4ull;
  if (ws_size < NEED) return;  // cannot proceed without scratch
  float* ws = (float*)d_ws;
  float* toks   = ws; ws += 1179648;   // [L,B,N,D]
  float* hbuf   = ws; ws += 2359296;   // normed rows (max 4608x512)
  float* qbuf   = ws; ws += 1179648;   // [2304,512]
  float* kvbuf  = ws; ws += 2359296;   // [12,192,1024]
  float* obuf   = ws; ws += 1179648;   // [2304,512]
  float* msgbuf = ws; ws += 2359296;   // [2,L,B,N,D]
  float* zbuf   = ws; ws += 6289920;   // [2304,2730]
  float* actbuf = ws; ws += 3144960;   // [2304,1365]
  float* kvpool = ws; ws += 4718592;   // [<=12,384,1024]
  float* Kc     = ws; ws += 15335424;  // [78,2,192,512]
  float* Vc     = ws; ws += 15335424;  // [78,2,192,512]
  float* robuf  = ws; ws += 196608;    // [384,512]
  float* robuf2 = ws; ws += 196608;    // [384,512]
  float* ronorm = ws; ws += 196608;    // [384,512]
  float* rqn    = ws; ws += 512;
  float* rq     = ws; ws += 512;

  auto gemm = [&](const float* A, const float* W, const float* bias, float* C,
                  int M, int N, int K,
                  long long aStr, long long wStr, long long bStr, long long cStr,
                  int nb) {
    dim3 g((N + TS - 1) / TS, (M + TS - 1) / TS, nb);
    hipLaunchKernelGGL(gemm_kernel, g, dim3(256), 0, stream,
                       A, W, bias, C, M, N, K, aStr, wStr, bStr, cStr);
  };

  // ---- init: toks = broadcast(tokens); cache msg0 kv entries e=0..5 ----
  {
    const int total = 6 * 2 * 192 * 512;
    hipLaunchKernelGGL(bcast_kernel, dim3((total + 255) / 256), dim3(256), 0, stream,
                       tokens, toks);
  }
  hipLaunchKernelGGL(rmsnorm_kernel, dim3(2304), dim3(256), 0, stream,
                     toks, res_nw, hbuf, 2304);
  gemm(hbuf, res_kvw, nullptr, kvpool, 384, 1024, 512, 196608, 0, 0, 393216, 6);
  hipLaunchKernelGGL(cache_fill_kernel, dim3(192, 12), dim3(128), 0, stream,
                     kvpool, res_knw, Kc, Vc, 0);

  for (int it = 0; it < 6; ++it) {
    // ---- block self-attention -> msgbuf[0] ----
    hipLaunchKernelGGL(rmsnorm_kernel, dim3(2304), dim3(256), 0, stream,
                       toks, attn_nw, hbuf, 384);
    gemm(hbuf, attn_qw, nullptr, qbuf, 384, 512, 512, 196608, 262144, 0, 196608, 6);
    gemm(hbuf, attn_kvw, nullptr, kvbuf, 384, 1024, 512, 196608, 524288, 0, 393216, 6);
    hipLaunchKernelGGL(block_attn_kernel, dim3(192, 8, 12), dim3(64), 0, stream,
                       qbuf, kvbuf, obuf);
    gemm(obuf, attn_ow, nullptr, msgbuf, 384, 512, 512, 196608, 262144, 0, 196608, 6);
    // ---- GEGLU FF -> msgbuf[1] ----
    hipLaunchKernelGGL(rmsnorm_kernel, dim3(2304), dim3(256), 0, stream,
                       toks, ff_nw, hbuf, 384);
    gemm(hbuf, ff_kw, ff_kb, zbuf, 384, 2730, 512, 196608, 1397760, 2730, 1048320, 6);
    hipLaunchKernelGGL(geglu_kernel, dim3(2304), dim3(256), 0, stream, zbuf, actbuf);
    gemm(actbuf, ff_vw, ff_vb, msgbuf + 1179648, 384, 512, 1365,
         524160, 698880, 512, 196608, 6);
    // ---- cache kv for the two new messages (entries (2it+1)*6 .. +11) ----
    hipLaunchKernelGGL(rmsnorm_kernel, dim3(4608), dim3(256), 0, stream,
                       msgbuf, res_nw, hbuf, 4608);
    gemm(hbuf, res_kvw, nullptr, kvpool, 384, 1024, 512, 196608, 0, 0, 393216, 12);
    hipLaunchKernelGGL(cache_fill_kernel, dim3(192, 24), dim3(128), 0, stream,
                       kvpool, res_knw, Kc, Vc, (2 * it + 1) * 6);
    if (it == 5) break;
    // ---- pooled cross-attention over all cached entries -> new toks ----
    hipLaunchKernelGGL(rmsnorm_kernel, dim3(2304), dim3(256), 0, stream,
                       toks, res_nw, hbuf, 2304);
    gemm(hbuf, res_qw, nullptr, qbuf, 2304, 512, 512, 0, 0, 0, 0, 1);
    hipLaunchKernelGGL(pooled_attn_kernel, dim3(192, 8, 12), dim3(64), 0, stream,
                       qbuf, Kc, Vc, obuf, (3 + 2 * it) * 6, 0);
    gemm(obuf, res_ow, nullptr, toks, 2304, 512, 512, 0, 0, 0, 0, 1);
  }

  // ---- readout ----
  hipLaunchKernelGGL(rmsnorm_kernel, dim3(1), dim3(256), 0, stream,
                     q_ro, res_nw, rqn, 1);
  gemm(rqn, res_qw, nullptr, rq, 1, 512, 512, 0, 0, 0, 0, 1);
  hipLaunchKernelGGL(pooled_attn_kernel, dim3(192, 8, 2), dim3(64), 0, stream,
                     rq, Kc, Vc, robuf, 78, 1);
  gemm(robuf, res_ow, nullptr, robuf2, 384, 512, 512, 0, 0, 0, 0, 1);
  hipLaunchKernelGGL(rmsnorm_kernel, dim3(384), dim3(256), 0, stream,
                     robuf2, ro_nw, ronorm, 384);
  gemm(ronorm, ro_w, nullptr, out, 384, 32000, 512, 0, 0, 0, 0, 1);
}

// Round 5
// 3758.675 us; speedup vs baseline: 2.0895x; 2.0895x over previous
//
#include <hip/hip_runtime.h>
#include <hip/hip_bf16.h>
#include <math.h>

// ---------------------------------------------------------------------------
// DepthlessTransformer forward. Round 5: split-bf16 MFMA GEMMs with IN-KERNEL
// split (A/W staged fp32, split to hi/lo bf16 after ds_read, 3 MFMAs:
// Ah*Wh + Al*Wh + Ah*Wl, fp32 accumulate). Rounds 3/4 post-mortem: their
// 352MB workspace exceeded ws_size -> early return -> zero output (absmax
// 2.4375 == max|ref|). This design needs 217.1MB < 224.1MB (round-1-proven).
// GEGLU fused into the FF-keys GEMM epilogue via interleaved weight copy.
// All attention/softmax/cache math fp32 (round-1 proven, absmax 0.0156).
// D=512 H=8 DH=64 DI=512 L=6 NEX=6 FFI=1365 V=32000 B=2 N=192
// ---------------------------------------------------------------------------

#define EPSV 1.1920929e-07f
typedef __hip_bfloat16 bf16;
typedef __attribute__((ext_vector_type(4))) float f32x4;
typedef __attribute__((ext_vector_type(8))) short bf16x8;

__device__ inline void split8(const float* p, bf16x8& h8, bf16x8& l8) {
  f32x4 x0 = *(const f32x4*)(p);
  f32x4 x1 = *(const f32x4*)(p + 4);
#pragma unroll
  for (int i = 0; i < 4; ++i) {
    bf16 h0 = __float2bfloat16(x0[i]);
    bf16 l0 = __float2bfloat16(x0[i] - __bfloat162float(h0));
    h8[i] = __builtin_bit_cast(short, h0);
    l8[i] = __builtin_bit_cast(short, l0);
    bf16 h1 = __float2bfloat16(x1[i]);
    bf16 l1 = __float2bfloat16(x1[i] - __bfloat162float(h1));
    h8[i + 4] = __builtin_bit_cast(short, h1);
    l8[i + 4] = __builtin_bit_cast(short, l1);
  }
}

#define GLDS(src, dst) __builtin_amdgcn_global_load_lds( \
    (const __attribute__((address_space(1))) void*)(src), \
    (__attribute__((address_space(3))) void*)(dst), 16, 0, 0)

// ============== split-on-read GEMM: C = A * W^T (+bias), fp32 in/out =======
// A: [M,K] fp32 (batch stride aStr); W: [Nt,K] fp32 (batch stride wStr),
// Nt = N rounded up to 128 rows readable. C: [M,ldc] fp32. K % 32 == 0.
// mode 0: plain (+optional bias). mode 1: GEGLU fused -- W rows interleaved
// (2c=sim_c, 2c+1=gate_c), writes act[row][col>>1] = z_sim*gelu(z_gate).
#define BM 128
#define BN 128
#define BKG 32
__global__ __launch_bounds__(256) void gemm_f32split_kernel(
    const float* __restrict__ A, const float* __restrict__ W,
    const float* __restrict__ bias, float* __restrict__ C,
    int M, int N, int K, int ldc,
    long long aStr, long long wStr, long long bStr, long long cStr, int mode)
{
  int batch = blockIdx.z;
  A += (size_t)batch * aStr;
  W += (size_t)batch * wStr;
  C += (size_t)batch * cStr;
  if (bias) bias += (size_t)batch * bStr;
  int m0 = blockIdx.y * BM, n0 = blockIdx.x * BN;

  __shared__ float As[BM][BKG];   // 16 KB
  __shared__ float Ws[BN][BKG];   // 16 KB

  int t = threadIdx.x;
  int wave = t >> 6, lane = t & 63;
  int wr = wave >> 1, wc = wave & 1;       // wave's 64x64 quadrant
  int srow = lane >> 3;                    // staging: 8 rows per 1KB chunk
  int scol = (lane & 7) * 4;               // 4 floats (16B) per lane
  int fr = lane & 15, fq = lane >> 4;      // fragment row + k-group

  f32x4 acc[4][4] = {};

  for (int k0 = 0; k0 < K; k0 += BKG) {
#pragma unroll
    for (int c = 0; c < 4; ++c) {
      int rbase = wave * 32 + c * 8;       // 8-row chunk
      const float* gA = A + (size_t)(m0 + rbase + srow) * K + k0 + scol;
      GLDS(gA, &As[rbase][0]);
      const float* gW = W + (size_t)(n0 + rbase + srow) * K + k0 + scol;
      GLDS(gW, &Ws[rbase][0]);
    }
    __syncthreads();  // drains vmcnt before compute
    bf16x8 ah[4], al[4], wh[4], wl[4];
#pragma unroll
    for (int m = 0; m < 4; ++m)
      split8(&As[wr * 64 + m * 16 + fr][fq * 8], ah[m], al[m]);
#pragma unroll
    for (int n = 0; n < 4; ++n)
      split8(&Ws[wc * 64 + n * 16 + fr][fq * 8], wh[n], wl[n]);
#pragma unroll
    for (int m = 0; m < 4; ++m)
#pragma unroll
      for (int n = 0; n < 4; ++n) {
        acc[m][n] = __builtin_amdgcn_mfma_f32_16x16x32_bf16(ah[m], wh[n], acc[m][n], 0, 0, 0);
        acc[m][n] = __builtin_amdgcn_mfma_f32_16x16x32_bf16(al[m], wh[n], acc[m][n], 0, 0, 0);
        acc[m][n] = __builtin_amdgcn_mfma_f32_16x16x32_bf16(ah[m], wl[n], acc[m][n], 0, 0, 0);
      }
    __syncthreads();
  }

  if (mode == 0) {
#pragma unroll
    for (int m = 0; m < 4; ++m)
#pragma unroll
      for (int n = 0; n < 4; ++n) {
        int col = n0 + wc * 64 + n * 16 + fr;
        if (col >= N) continue;
        float bv = bias ? bias[col] : 0.f;
#pragma unroll
        for (int j = 0; j < 4; ++j) {
          int row = m0 + wr * 64 + m * 16 + fq * 4 + j;
          if (row < M) C[(size_t)row * ldc + col] = acc[m][n][j] + bv;
        }
      }
  } else {
    // GEGLU: even col = sim, odd col = gate (interleaved weight rows).
    // bias is padded to the full tiled width, so bias[col] always readable;
    // padded cols have zero W rows + zero bias -> z = 0 (finite, unused).
#pragma unroll
    for (int m = 0; m < 4; ++m)
#pragma unroll
      for (int n = 0; n < 4; ++n) {
        int col = n0 + wc * 64 + n * 16 + fr;
        float bv = bias[col];
#pragma unroll
        for (int j = 0; j < 4; ++j) {
          float z = acc[m][n][j] + bv;
          float zn = __shfl_xor(z, 1);   // partner: sim<->gate
          if (!(col & 1) && col < N) {
            float g = zn;
            float a = z * (0.5f * g * (1.f + erff(g * 0.70710678118654752f)));
            int row = m0 + wr * 64 + m * 16 + fq * 4 + j;
            if (row < M) C[(size_t)row * ldc + (col >> 1)] = a;
          }
        }
      }
  }
}

// ====== FF-keys weight perm+pad: [6,2730,512] -> [6,2816,512] interleaved ==
__global__ void ffk_perm_kernel(const float* __restrict__ kw,
                                const float* __restrict__ kb,
                                float* __restrict__ wout, float* __restrict__ bout)
{
  size_t idx = (size_t)blockIdx.x * 256 + threadIdx.x;
  const size_t per = 2816ull * 512;
  if (idx < 6 * per) {
    int b = (int)(idx / per);
    size_t r2 = idx % per;
    int r = (int)(r2 >> 9), k = (int)(r2 & 511);
    float v = 0.f;
    if (r < 2730) {
      int c = (r >> 1) + (r & 1) * 1365;
      v = kw[((size_t)b * 2730 + c) * 512 + k];
    }
    wout[idx] = v;
  }
  if (idx < 6 * 2816) {
    int b = (int)(idx / 2816), r = (int)(idx % 2816);
    float v = 0.f;
    if (r < 2730) {
      int c = (r >> 1) + (r & 1) * 1365;
      v = kb[(size_t)b * 2730 + c];
    }
    bout[idx] = v;
  }
}

// ====== FF-vals weight pad: [6,512,1365] -> [6,512,1408] (K zero-pad) ======
__global__ void ffv_pad_kernel(const float* __restrict__ vw, float* __restrict__ wout)
{
  size_t idx = (size_t)blockIdx.x * 256 + threadIdx.x;
  const size_t total = 6ull * 512 * 1408;
  if (idx >= total) return;
  int k = (int)(idx % 1408);
  size_t nr = idx / 1408;   // b*512 + n
  wout[idx] = (k < 1365) ? vw[nr * 1365 + k] : 0.f;
}

// ================= rmsnorm over dim 512 (fp32 -> fp32) =====================
__global__ __launch_bounds__(256) void rmsnorm_kernel(
    const float* __restrict__ x, const float* __restrict__ w,
    float* __restrict__ out, int rows_per_w)
{
  int r = blockIdx.x;
  int t = threadIdx.x;
  const float* xr = x + (size_t)r * 512;
  float a = xr[t], b = xr[t + 256];
  float ss = a * a + b * b;
  for (int off = 32; off; off >>= 1) ss += __shfl_xor(ss, off);
  __shared__ float wsum[4];
  if ((t & 63) == 0) wsum[t >> 6] = ss;
  __syncthreads();
  float tot = wsum[0] + wsum[1] + wsum[2] + wsum[3];
  float rs = rsqrtf(tot * (1.f / 512.f) + EPSV);
  const float* wr = w + (size_t)(r / rows_per_w) * 512;
  out[(size_t)r * 512 + t] = a * rs * wr[t];
  out[(size_t)r * 512 + t + 256] = b * rs * wr[t + 256];
}

// ================= broadcast tokens -> toks[L] =============================
__global__ void bcast_kernel(const float* __restrict__ tokens, float* __restrict__ toks)
{
  size_t idx = (size_t)blockIdx.x * 256 + threadIdx.x;
  const size_t total = (size_t)6 * 2 * 192 * 512;
  if (idx >= total) return;
  toks[idx] = tokens[idx % ((size_t)2 * 192 * 512)];
}

// ================= fused per-row block self-attention (fp32) ===============
__global__ __launch_bounds__(64) void block_attn_kernel(
    const float* __restrict__ q, const float* __restrict__ kv, float* __restrict__ o)
{
  int i = blockIdx.x, h = blockIdx.y, lb = blockIdx.z;
  int lane = threadIdx.x;
  __shared__ float qs[64];
  __shared__ float p[192];
  const float* qrow = q + ((size_t)(lb * 192 + i)) * 512 + h * 64;
  qs[lane] = qrow[lane];
  __syncthreads();
  const float* kb = kv + (size_t)lb * 192 * 1024 + h * 64;
  float s[3];
#pragma unroll
  for (int r = 0; r < 3; ++r) {
    int j = lane + r * 64;
    const float* krow = kb + (size_t)j * 1024;
    float acc = 0.f;
    for (int d = 0; d < 64; ++d) acc += qs[d] * krow[d];
    s[r] = acc;
  }
  float mx = fmaxf(fmaxf(s[0], s[1]), s[2]);
  for (int off = 32; off; off >>= 1) mx = fmaxf(mx, __shfl_xor(mx, off));
  float sum = 0.f;
#pragma unroll
  for (int r = 0; r < 3; ++r) { s[r] = expf(s[r] - mx); sum += s[r]; }
  for (int off = 32; off; off >>= 1) sum += __shfl_xor(sum, off);
  float inv = 1.f / sum;
#pragma unroll
  for (int r = 0; r < 3; ++r) p[lane + r * 64] = s[r] * inv;
  __syncthreads();
  const float* vb = kb + 512;
  float acc = 0.f;
  for (int j = 0; j < 192; ++j) acc += p[j] * vb[(size_t)j * 1024 + lane];
  o[((size_t)(lb * 192 + i)) * 512 + h * 64 + lane] = acc;
}

// ================= fused pooled attention (fp32) ===========================
__global__ __launch_bounds__(64) void pooled_attn_kernel(
    const float* __restrict__ q, const float* __restrict__ Kc,
    const float* __restrict__ Vc, float* __restrict__ o, int M, int single_q)
{
  int n = blockIdx.x, h = blockIdx.y, j = blockIdx.z;
  int lane = threadIdx.x;
  int ctx_b = single_q ? j : (j / 6);
  __shared__ float qs[64];
  __shared__ float p[128];
  const float* qrow = single_q ? (q + h * 64)
                               : (q + ((size_t)(j * 192 + n)) * 512 + h * 64);
  qs[lane] = qrow[lane];
  __syncthreads();
  float s0 = -1e30f, s1 = -1e30f;
  if (lane < M) {
    const float* krow = Kc + (((size_t)lane * 2 + ctx_b) * 192 + n) * 512 + h * 64;
    float acc = 0.f;
    for (int d = 0; d < 64; ++d) acc += qs[d] * krow[d];
    s0 = acc;
  }
  int m1 = lane + 64;
  if (m1 < M) {
    const float* krow = Kc + (((size_t)m1 * 2 + ctx_b) * 192 + n) * 512 + h * 64;
    float acc = 0.f;
    for (int d = 0; d < 64; ++d) acc += qs[d] * krow[d];
    s1 = acc;
  }
  float mx = fmaxf(s0, s1);
  for (int off = 32; off; off >>= 1) mx = fmaxf(mx, __shfl_xor(mx, off));
  float e0 = (lane < M) ? expf(s0 - mx) : 0.f;
  float e1 = (m1 < M) ? expf(s1 - mx) : 0.f;
  float sum = e0 + e1;
  for (int off = 32; off; off >>= 1) sum += __shfl_xor(sum, off);
  float inv = 1.f / sum;
  p[lane] = e0 * inv;
  if (m1 < M) p[m1] = e1 * inv;
  __syncthreads();
  float acc = 0.f;
  for (int m = 0; m < M; ++m)
    acc += p[m] * Vc[(((size_t)m * 2 + ctx_b) * 192 + n) * 512 + h * 64 + lane];
  o[((size_t)(j * 192 + n)) * 512 + h * 64 + lane] = acc;
}

// ================= kv-cache fill (fp32, per-head key rmsnorm) ==============
__global__ __launch_bounds__(128) void cache_fill_kernel(
    const float* __restrict__ kvp, const float* __restrict__ knw,
    float* __restrict__ Kc, float* __restrict__ Vc, int base_e)
{
  int n = blockIdx.x;
  int t = blockIdx.y;
  int g = t >> 1, b = t & 1;
  int e = base_e + g;
  int lane = threadIdx.x;  // 128 lanes x 4 cols; 16 lanes per head
  const float* src = kvp + ((size_t)t * 192 + n) * 1024;
  float k4[4];
  float ss = 0.f;
#pragma unroll
  for (int u = 0; u < 4; ++u) { k4[u] = src[lane * 4 + u]; ss += k4[u] * k4[u]; }
  for (int off = 8; off; off >>= 1) ss += __shfl_xor(ss, off, 16);
  float rs = rsqrtf(ss * (1.f / 64.f) + EPSV);
  float* kd = Kc + (((size_t)e * 2 + b) * 192 + n) * 512;
  float* vd = Vc + (((size_t)e * 2 + b) * 192 + n) * 512;
#pragma unroll
  for (int u = 0; u < 4; ++u) {
    int c = lane * 4 + u;
    kd[c] = k4[u] * rs * knw[c & 63];
    vd[c] = src[512 + c];
  }
}

// ===========================================================================
extern "C" void kernel_launch(void* const* d_in, const int* in_sizes, int n_in,
                              void* d_out, int out_size, void* d_ws, size_t ws_size,
                              hipStream_t stream)
{
  const float* tokens   = (const float*)d_in[0];
  const float* attn_nw  = (const float*)d_in[1];
  const float* attn_qw  = (const float*)d_in[2];
  const float* attn_kvw = (const float*)d_in[3];
  const float* attn_ow  = (const float*)d_in[4];
  const float* ff_nw    = (const float*)d_in[5];
  const float* ff_kw    = (const float*)d_in[6];
  const float* ff_kb    = (const float*)d_in[7];
  const float* ff_vw    = (const float*)d_in[8];
  const float* ff_vb    = (const float*)d_in[9];
  const float* res_nw   = (const float*)d_in[10];
  const float* res_knw  = (const float*)d_in[11];
  const float* res_qw   = (const float*)d_in[12];
  const float* res_kvw  = (const float*)d_in[13];
  const float* res_ow   = (const float*)d_in[14];
  const float* q_ro     = (const float*)d_in[15];
  const float* ro_nw    = (const float*)d_in[16];
  const float* ro_w     = (const float*)d_in[17];
  float* out = (float*)d_out;

  // ---- workspace carve-up (54,281,728 floats = 217.1 MB) ----
  float* ws = (float*)d_ws;
  const size_t NEED = 54281728ull * 4ull;
  if (ws_size < NEED) return;
  float* ffk_w   = ws;  ws += 6ull * 2816 * 512;   // 8,650,752 (perm+pad fp32)
  float* ffk_b   = ws;  ws += 6ull * 2816;         // 16,896
  float* ffv_w   = ws;  ws += 6ull * 512 * 1408;   // 4,325,376 (K-pad fp32)
  float* toks    = ws;  ws += 1179648;             // [6,2,192,512]
  float* hbuf    = ws;  ws += 2359296;             // [<=4608,512]
  float* msgbuf  = ws;  ws += 2359296;             // [2,6,2,192,512]
  float* scratch = ws;  ws += 4718592;             // union region
  float* rqn     = ws;  ws += 512;
  float* rq      = ws;  ws += 512;
  float* Kc      = ws;  ws += 15335424;            // [78,2,192,512]
  float* Vc      = ws;  ws += 15335424;
  // scratch union (all uses strictly serialized on `stream`):
  float* qbuf   = scratch;                 // [2304,512]
  float* kvbuf  = scratch + 1179648;       // [12,192,1024]
  float* obuf   = scratch + 3538944;       // [2304,512]
  float* kvpool = scratch;                 // [<=24,192,1024] = 4,718,592
  float* act    = scratch;                 // [2304,1408] = 3,244,032
  // readout aliases (msgbuf dead by then):
  float* robuf  = msgbuf;                  // [384,512]
  float* robuf2 = msgbuf + 196608;         // [384,512]
  float* ronorm = msgbuf + 393216;         // [384,512]

  auto gemm = [&](const float* A, const float* W, const float* bias, float* C,
                  int M, int N, int K, int ldc,
                  long long aStr, long long wStr, long long bStr, long long cStr,
                  int nb, int mode) {
    dim3 g((N + BN - 1) / BN, (M + BM - 1) / BM, nb);
    hipLaunchKernelGGL(gemm_f32split_kernel, g, dim3(256), 0, stream,
                       A, W, bias, C, M, N, K, ldc, aStr, wStr, bStr, cStr, mode);
  };

  // ---- FF weight prep (perm+pad) ----
  hipLaunchKernelGGL(ffk_perm_kernel, dim3((unsigned)((6ull * 2816 * 512 + 255) / 256)),
                     dim3(256), 0, stream, ff_kw, ff_kb, ffk_w, ffk_b);
  hipLaunchKernelGGL(ffv_pad_kernel, dim3((unsigned)((6ull * 512 * 1408 + 255) / 256)),
                     dim3(256), 0, stream, ff_vw, ffv_w);

  // ---- init: toks = broadcast(tokens); cache msg0 kv entries 0..5 ----
  {
    const int total = 6 * 2 * 192 * 512;
    hipLaunchKernelGGL(bcast_kernel, dim3((total + 255) / 256), dim3(256), 0, stream,
                       tokens, toks);
  }
  hipLaunchKernelGGL(rmsnorm_kernel, dim3(2304), dim3(256), 0, stream,
                     toks, res_nw, hbuf, 2304);
  gemm(hbuf, res_kvw, nullptr, kvpool, 384, 1024, 512, 1024,
       196608, 0, 0, 393216, 6, 0);
  hipLaunchKernelGGL(cache_fill_kernel, dim3(192, 12), dim3(128), 0, stream,
                     kvpool, res_knw, Kc, Vc, 0);

  for (int it = 0; it < 6; ++it) {
    // ---- block self-attention -> msgbuf[0] ----
    hipLaunchKernelGGL(rmsnorm_kernel, dim3(2304), dim3(256), 0, stream,
                       toks, attn_nw, hbuf, 384);
    gemm(hbuf, attn_qw, nullptr, qbuf, 384, 512, 512, 512,
         196608, 262144, 0, 196608, 6, 0);
    gemm(hbuf, attn_kvw, nullptr, kvbuf, 384, 1024, 512, 1024,
         196608, 524288, 0, 393216, 6, 0);
    hipLaunchKernelGGL(block_attn_kernel, dim3(192, 8, 12), dim3(64), 0, stream,
                       qbuf, kvbuf, obuf);
    gemm(obuf, attn_ow, nullptr, msgbuf, 384, 512, 512, 512,
         196608, 262144, 0, 196608, 6, 0);
    // ---- GEGLU FF (fused) -> msgbuf[1] ----
    hipLaunchKernelGGL(rmsnorm_kernel, dim3(2304), dim3(256), 0, stream,
                       toks, ff_nw, hbuf, 384);
    gemm(hbuf, ffk_w, ffk_b, act, 384, 2730, 512, 1408,
         196608, 1441792, 2816, 540672, 6, 1);       // clobbers qbuf/kvbuf (dead)
    gemm(act, ffv_w, ff_vb, msgbuf + 1179648, 384, 512, 1408, 512,
         540672, 720896, 512, 196608, 6, 0);
    // ---- cache kv for the two new messages ----
    hipLaunchKernelGGL(rmsnorm_kernel, dim3(4608), dim3(256), 0, stream,
                       msgbuf, res_nw, hbuf, 4608);
    gemm(hbuf, res_kvw, nullptr, kvpool, 384, 1024, 512, 1024,
         196608, 0, 0, 393216, 12, 0);               // clobbers act (dead)
    hipLaunchKernelGGL(cache_fill_kernel, dim3(192, 24), dim3(128), 0, stream,
                       kvpool, res_knw, Kc, Vc, (2 * it + 1) * 6);
    if (it == 5) break;
    // ---- pooled cross-attention over all cached entries -> new toks ----
    hipLaunchKernelGGL(rmsnorm_kernel, dim3(2304), dim3(256), 0, stream,
                       toks, res_nw, hbuf, 2304);
    gemm(hbuf, res_qw, nullptr, qbuf, 2304, 512, 512, 512,
         0, 0, 0, 0, 1, 0);                          // clobbers kvpool (dead)
    hipLaunchKernelGGL(pooled_attn_kernel, dim3(192, 8, 12), dim3(64), 0, stream,
                       qbuf, Kc, Vc, obuf, (3 + 2 * it) * 6, 0);
    gemm(obuf, res_ow, nullptr, toks, 2304, 512, 512, 512,
         0, 0, 0, 0, 1, 0);
  }

  // ---- readout ----
  hipLaunchKernelGGL(rmsnorm_kernel, dim3(1), dim3(256), 0, stream,
                     q_ro, res_nw, rqn, 1);
  gemm(rqn, res_qw, nullptr, rq, 1, 512, 512, 512, 0, 0, 0, 0, 1, 0);
  hipLaunchKernelGGL(pooled_attn_kernel, dim3(192, 8, 2), dim3(64), 0, stream,
                     rq, Kc, Vc, robuf, 78, 1);
  gemm(robuf, res_ow, nullptr, robuf2, 384, 512, 512, 512, 0, 0, 0, 0, 1, 0);
  hipLaunchKernelGGL(rmsnorm_kernel, dim3(384), dim3(256), 0, stream,
                     robuf2, ro_nw, ronorm, 384);
  gemm(ronorm, ro_w, nullptr, out, 384, 32000, 512, 32000, 0, 0, 0, 0, 1, 0);
}

// Round 6
// 3347.425 us; speedup vs baseline: 2.3462x; 1.1229x over previous
//
#include <hip/hip_runtime.h>
#include <hip/hip_bf16.h>
#include <math.h>

// ---------------------------------------------------------------------------
// DepthlessTransformer forward. Round 6: attention kernels rebuilt around
// LDS-staged K tiles (coalesced global loads, bank-conflict-free LDS reads).
// Round-5 counters: block_attn 6x218us, VALUBusy 12%, HBM 2.6% -> latency-
// bound transposed K reads (each lane walked its own 4KB-strided row).
// GEMMs unchanged: split-bf16 MFMA with in-kernel split (round-5 proven,
// absmax 0.015625). Workspace unchanged: 217.1 MB.
// D=512 H=8 DH=64 DI=512 L=6 NEX=6 FFI=1365 V=32000 B=2 N=192
// ---------------------------------------------------------------------------

#define EPSV 1.1920929e-07f
typedef __hip_bfloat16 bf16;
typedef __attribute__((ext_vector_type(4))) float f32x4;
typedef __attribute__((ext_vector_type(8))) short bf16x8;

__device__ inline void split8(const float* p, bf16x8& h8, bf16x8& l8) {
  f32x4 x0 = *(const f32x4*)(p);
  f32x4 x1 = *(const f32x4*)(p + 4);
#pragma unroll
  for (int i = 0; i < 4; ++i) {
    bf16 h0 = __float2bfloat16(x0[i]);
    bf16 l0 = __float2bfloat16(x0[i] - __bfloat162float(h0));
    h8[i] = __builtin_bit_cast(short, h0);
    l8[i] = __builtin_bit_cast(short, l0);
    bf16 h1 = __float2bfloat16(x1[i]);
    bf16 l1 = __float2bfloat16(x1[i] - __bfloat162float(h1));
    h8[i + 4] = __builtin_bit_cast(short, h1);
    l8[i + 4] = __builtin_bit_cast(short, l1);
  }
}

#define GLDS(src, dst) __builtin_amdgcn_global_load_lds( \
    (const __attribute__((address_space(1))) void*)(src), \
    (__attribute__((address_space(3))) void*)(dst), 16, 0, 0)

// ============== split-on-read GEMM: C = A * W^T (+bias), fp32 in/out =======
// A: [M,K] fp32 (batch stride aStr); W: [Nt,K] fp32 (batch stride wStr),
// Nt = N rounded up to 128 rows readable. C: [M,ldc] fp32. K % 32 == 0.
// mode 0: plain (+optional bias). mode 1: GEGLU fused -- W rows interleaved
// (2c=sim_c, 2c+1=gate_c), writes act[row][col>>1] = z_sim*gelu(z_gate).
#define BM 128
#define BN 128
#define BKG 32
__global__ __launch_bounds__(256) void gemm_f32split_kernel(
    const float* __restrict__ A, const float* __restrict__ W,
    const float* __restrict__ bias, float* __restrict__ C,
    int M, int N, int K, int ldc,
    long long aStr, long long wStr, long long bStr, long long cStr, int mode)
{
  int batch = blockIdx.z;
  A += (size_t)batch * aStr;
  W += (size_t)batch * wStr;
  C += (size_t)batch * cStr;
  if (bias) bias += (size_t)batch * bStr;
  int m0 = blockIdx.y * BM, n0 = blockIdx.x * BN;

  __shared__ float As[BM][BKG];   // 16 KB
  __shared__ float Ws[BN][BKG];   // 16 KB

  int t = threadIdx.x;
  int wave = t >> 6, lane = t & 63;
  int wr = wave >> 1, wc = wave & 1;       // wave's 64x64 quadrant
  int srow = lane >> 3;                    // staging: 8 rows per 1KB chunk
  int scol = (lane & 7) * 4;               // 4 floats (16B) per lane
  int fr = lane & 15, fq = lane >> 4;      // fragment row + k-group

  f32x4 acc[4][4] = {};

  for (int k0 = 0; k0 < K; k0 += BKG) {
#pragma unroll
    for (int c = 0; c < 4; ++c) {
      int rbase = wave * 32 + c * 8;       // 8-row chunk
      const float* gA = A + (size_t)(m0 + rbase + srow) * K + k0 + scol;
      GLDS(gA, &As[rbase][0]);
      const float* gW = W + (size_t)(n0 + rbase + srow) * K + k0 + scol;
      GLDS(gW, &Ws[rbase][0]);
    }
    __syncthreads();  // drains vmcnt before compute
    bf16x8 ah[4], al[4], wh[4], wl[4];
#pragma unroll
    for (int m = 0; m < 4; ++m)
      split8(&As[wr * 64 + m * 16 + fr][fq * 8], ah[m], al[m]);
#pragma unroll
    for (int n = 0; n < 4; ++n)
      split8(&Ws[wc * 64 + n * 16 + fr][fq * 8], wh[n], wl[n]);
#pragma unroll
    for (int m = 0; m < 4; ++m)
#pragma unroll
      for (int n = 0; n < 4; ++n) {
        acc[m][n] = __builtin_amdgcn_mfma_f32_16x16x32_bf16(ah[m], wh[n], acc[m][n], 0, 0, 0);
        acc[m][n] = __builtin_amdgcn_mfma_f32_16x16x32_bf16(al[m], wh[n], acc[m][n], 0, 0, 0);
        acc[m][n] = __builtin_amdgcn_mfma_f32_16x16x32_bf16(ah[m], wl[n], acc[m][n], 0, 0, 0);
      }
    __syncthreads();
  }

  if (mode == 0) {
#pragma unroll
    for (int m = 0; m < 4; ++m)
#pragma unroll
      for (int n = 0; n < 4; ++n) {
        int col = n0 + wc * 64 + n * 16 + fr;
        if (col >= N) continue;
        float bv = bias ? bias[col] : 0.f;
#pragma unroll
        for (int j = 0; j < 4; ++j) {
          int row = m0 + wr * 64 + m * 16 + fq * 4 + j;
          if (row < M) C[(size_t)row * ldc + col] = acc[m][n][j] + bv;
        }
      }
  } else {
    // GEGLU: even col = sim, odd col = gate (interleaved weight rows).
#pragma unroll
    for (int m = 0; m < 4; ++m)
#pragma unroll
      for (int n = 0; n < 4; ++n) {
        int col = n0 + wc * 64 + n * 16 + fr;
        float bv = bias[col];
#pragma unroll
        for (int j = 0; j < 4; ++j) {
          float z = acc[m][n][j] + bv;
          float zn = __shfl_xor(z, 1);   // partner: sim<->gate
          if (!(col & 1) && col < N) {
            float g = zn;
            float a = z * (0.5f * g * (1.f + erff(g * 0.70710678118654752f)));
            int row = m0 + wr * 64 + m * 16 + fq * 4 + j;
            if (row < M) C[(size_t)row * ldc + (col >> 1)] = a;
          }
        }
      }
  }
}

// ====== FF-keys weight perm+pad: [6,2730,512] -> [6,2816,512] interleaved ==
__global__ void ffk_perm_kernel(const float* __restrict__ kw,
                                const float* __restrict__ kb,
                                float* __restrict__ wout, float* __restrict__ bout)
{
  size_t idx = (size_t)blockIdx.x * 256 + threadIdx.x;
  const size_t per = 2816ull * 512;
  if (idx < 6 * per) {
    int b = (int)(idx / per);
    size_t r2 = idx % per;
    int r = (int)(r2 >> 9), k = (int)(r2 & 511);
    float v = 0.f;
    if (r < 2730) {
      int c = (r >> 1) + (r & 1) * 1365;
      v = kw[((size_t)b * 2730 + c) * 512 + k];
    }
    wout[idx] = v;
  }
  if (idx < 6 * 2816) {
    int b = (int)(idx / 2816), r = (int)(idx % 2816);
    float v = 0.f;
    if (r < 2730) {
      int c = (r >> 1) + (r & 1) * 1365;
      v = kb[(size_t)b * 2730 + c];
    }
    bout[idx] = v;
  }
}

// ====== FF-vals weight pad: [6,512,1365] -> [6,512,1408] (K zero-pad) ======
__global__ void ffv_pad_kernel(const float* __restrict__ vw, float* __restrict__ wout)
{
  size_t idx = (size_t)blockIdx.x * 256 + threadIdx.x;
  const size_t total = 6ull * 512 * 1408;
  if (idx >= total) return;
  int k = (int)(idx % 1408);
  size_t nr = idx / 1408;   // b*512 + n
  wout[idx] = (k < 1365) ? vw[nr * 1365 + k] : 0.f;
}

// ================= rmsnorm over dim 512 (fp32 -> fp32) =====================
__global__ __launch_bounds__(256) void rmsnorm_kernel(
    const float* __restrict__ x, const float* __restrict__ w,
    float* __restrict__ out, int rows_per_w)
{
  int r = blockIdx.x;
  int t = threadIdx.x;
  const float* xr = x + (size_t)r * 512;
  float a = xr[t], b = xr[t + 256];
  float ss = a * a + b * b;
  for (int off = 32; off; off >>= 1) ss += __shfl_xor(ss, off);
  __shared__ float wsum[4];
  if ((t & 63) == 0) wsum[t >> 6] = ss;
  __syncthreads();
  float tot = wsum[0] + wsum[1] + wsum[2] + wsum[3];
  float rs = rsqrtf(tot * (1.f / 512.f) + EPSV);
  const float* wr = w + (size_t)(r / rows_per_w) * 512;
  out[(size_t)r * 512 + t] = a * rs * wr[t];
  out[(size_t)r * 512 + t + 256] = b * rs * wr[t + 256];
}

// ================= broadcast tokens -> toks[L] =============================
__global__ void bcast_kernel(const float* __restrict__ tokens, float* __restrict__ toks)
{
  size_t idx = (size_t)blockIdx.x * 256 + threadIdx.x;
  const size_t total = (size_t)6 * 2 * 192 * 512;
  if (idx >= total) return;
  toks[idx] = tokens[idx % ((size_t)2 * 192 * 512)];
}

// ================= block self-attention, LDS-staged K ======================
// q: [12,192,512]; kv: [12,192,1024] (k 0..511, v 512..1023); o: [12,192,512]
// grid (48, 8, 12), 256 threads = 4 waves; wave w handles query i = bx*4+w.
// K tile [192][64] staged coalesced into LDS (pad 65: QK reads 2-way = free).
__global__ __launch_bounds__(256) void block_attn_kernel(
    const float* __restrict__ q, const float* __restrict__ kv, float* __restrict__ o)
{
  int h = blockIdx.y, lb = blockIdx.z;
  int t = threadIdx.x;
  int wave = t >> 6, lane = t & 63;
  int i = blockIdx.x * 4 + wave;

  __shared__ float Ks[192][65];   // 49,920 B
  __shared__ float qs[4][64];
  __shared__ float ps[4][192];

  const float* kb = kv + (size_t)lb * 192 * 1024 + h * 64;
  // stage K: 192 rows x 64 cols; linear idx = c*256 + t, row = idx>>6
#pragma unroll
  for (int c = 0; c < 48; ++c) {
    int idx = c * 256 + t;
    int row = idx >> 6, col = idx & 63;
    Ks[row][col] = kb[(size_t)row * 1024 + col];
  }
  const float* qrow = q + ((size_t)(lb * 192 + i)) * 512 + h * 64;
  qs[wave][lane] = qrow[lane];
  __syncthreads();

  float s[3];
#pragma unroll
  for (int r = 0; r < 3; ++r) {
    int j = lane + r * 64;
    float acc = 0.f;
#pragma unroll 8
    for (int d = 0; d < 64; ++d) acc += qs[wave][d] * Ks[j][d];
    s[r] = acc;
  }
  float mx = fmaxf(fmaxf(s[0], s[1]), s[2]);
  for (int off = 32; off; off >>= 1) mx = fmaxf(mx, __shfl_xor(mx, off));
  float sum = 0.f;
#pragma unroll
  for (int r = 0; r < 3; ++r) { s[r] = expf(s[r] - mx); sum += s[r]; }
  for (int off = 32; off; off >>= 1) sum += __shfl_xor(sum, off);
  float inv = 1.f / sum;
#pragma unroll
  for (int r = 0; r < 3; ++r) ps[wave][lane + r * 64] = s[r] * inv;
  // wave-internal producer/consumer only; shuffles keep wave converged
  const float* vb = kb + 512;
  float acc = 0.f;
  for (int j = 0; j < 192; ++j) acc += ps[wave][j] * vb[(size_t)j * 1024 + lane];
  o[((size_t)(lb * 192 + i)) * 512 + h * 64 + lane] = acc;
}

// ================= pooled attention, LDS-staged K ==========================
// Kc/Vc: fp32 [78,2,192,512]. intermediate: grid (192,8,12), q rows j*192+n,
// ctx batch j/6. readout: grid (192,8,2), single q row. 64 threads.
__global__ __launch_bounds__(64) void pooled_attn_kernel(
    const float* __restrict__ q, const float* __restrict__ Kc,
    const float* __restrict__ Vc, float* __restrict__ o, int M, int single_q)
{
  int n = blockIdx.x, h = blockIdx.y, j = blockIdx.z;
  int lane = threadIdx.x;
  int ctx_b = single_q ? j : (j / 6);

  __shared__ float Ks[80][65];   // 20,800 B
  __shared__ float qs[64];
  __shared__ float p[128];

  // stage K entries: one coalesced 256B row per entry
  for (int m = 0; m < M; ++m)
    Ks[m][lane] = Kc[(((size_t)m * 2 + ctx_b) * 192 + n) * 512 + h * 64 + lane];
  const float* qrow = single_q ? (q + h * 64)
                               : (q + ((size_t)(j * 192 + n)) * 512 + h * 64);
  qs[lane] = qrow[lane];
  __syncthreads();

  float s0 = -1e30f, s1 = -1e30f;
  if (lane < M) {
    float acc = 0.f;
#pragma unroll 8
    for (int d = 0; d < 64; ++d) acc += qs[d] * Ks[lane][d];
    s0 = acc;
  }
  int m1 = lane + 64;
  if (m1 < M) {
    float acc = 0.f;
#pragma unroll 8
    for (int d = 0; d < 64; ++d) acc += qs[d] * Ks[m1][d];
    s1 = acc;
  }
  float mx = fmaxf(s0, s1);
  for (int off = 32; off; off >>= 1) mx = fmaxf(mx, __shfl_xor(mx, off));
  float e0 = (lane < M) ? expf(s0 - mx) : 0.f;
  float e1 = (m1 < M) ? expf(s1 - mx) : 0.f;
  float sum = e0 + e1;
  for (int off = 32; off; off >>= 1) sum += __shfl_xor(sum, off);
  float inv = 1.f / sum;
  p[lane] = e0 * inv;
  if (m1 < M) p[m1] = e1 * inv;
  __syncthreads();
  float acc = 0.f;
  for (int m = 0; m < M; ++m)
    acc += p[m] * Vc[(((size_t)m * 2 + ctx_b) * 192 + n) * 512 + h * 64 + lane];
  o[((size_t)(j * 192 + n)) * 512 + h * 64 + lane] = acc;
}

// ================= kv-cache fill (fp32, per-head key rmsnorm) ==============
__global__ __launch_bounds__(128) void cache_fill_kernel(
    const float* __restrict__ kvp, const float* __restrict__ knw,
    float* __restrict__ Kc, float* __restrict__ Vc, int base_e)
{
  int n = blockIdx.x;
  int t = blockIdx.y;
  int g = t >> 1, b = t & 1;
  int e = base_e + g;
  int lane = threadIdx.x;  // 128 lanes x 4 cols; 16 lanes per head
  const float* src = kvp + ((size_t)t * 192 + n) * 1024;
  float k4[4];
  float ss = 0.f;
#pragma unroll
  for (int u = 0; u < 4; ++u) { k4[u] = src[lane * 4 + u]; ss += k4[u] * k4[u]; }
  for (int off = 8; off; off >>= 1) ss += __shfl_xor(ss, off, 16);
  float rs = rsqrtf(ss * (1.f / 64.f) + EPSV);
  float* kd = Kc + (((size_t)e * 2 + b) * 192 + n) * 512;
  float* vd = Vc + (((size_t)e * 2 + b) * 192 + n) * 512;
#pragma unroll
  for (int u = 0; u < 4; ++u) {
    int c = lane * 4 + u;
    kd[c] = k4[u] * rs * knw[c & 63];
    vd[c] = src[512 + c];
  }
}

// ===========================================================================
extern "C" void kernel_launch(void* const* d_in, const int* in_sizes, int n_in,
                              void* d_out, int out_size, void* d_ws, size_t ws_size,
                              hipStream_t stream)
{
  const float* tokens   = (const float*)d_in[0];
  const float* attn_nw  = (const float*)d_in[1];
  const float* attn_qw  = (const float*)d_in[2];
  const float* attn_kvw = (const float*)d_in[3];
  const float* attn_ow  = (const float*)d_in[4];
  const float* ff_nw    = (const float*)d_in[5];
  const float* ff_kw    = (const float*)d_in[6];
  const float* ff_kb    = (const float*)d_in[7];
  const float* ff_vw    = (const float*)d_in[8];
  const float* ff_vb    = (const float*)d_in[9];
  const float* res_nw   = (const float*)d_in[10];
  const float* res_knw  = (const float*)d_in[11];
  const float* res_qw   = (const float*)d_in[12];
  const float* res_kvw  = (const float*)d_in[13];
  const float* res_ow   = (const float*)d_in[14];
  const float* q_ro     = (const float*)d_in[15];
  const float* ro_nw    = (const float*)d_in[16];
  const float* ro_w     = (const float*)d_in[17];
  float* out = (float*)d_out;

  // ---- workspace carve-up (54,281,728 floats = 217.1 MB) ----
  float* ws = (float*)d_ws;
  const size_t NEED = 54281728ull * 4ull;
  if (ws_size < NEED) return;
  float* ffk_w   = ws;  ws += 6ull * 2816 * 512;   // 8,650,752 (perm+pad fp32)
  float* ffk_b   = ws;  ws += 6ull * 2816;         // 16,896
  float* ffv_w   = ws;  ws += 6ull * 512 * 1408;   // 4,325,376 (K-pad fp32)
  float* toks    = ws;  ws += 1179648;             // [6,2,192,512]
  float* hbuf    = ws;  ws += 2359296;             // [<=4608,512]
  float* msgbuf  = ws;  ws += 2359296;             // [2,6,2,192,512]
  float* scratch = ws;  ws += 4718592;             // union region
  float* rqn     = ws;  ws += 512;
  float* rq      = ws;  ws += 512;
  float* Kc      = ws;  ws += 15335424;            // [78,2,192,512]
  float* Vc      = ws;  ws += 15335424;
  // scratch union (all uses strictly serialized on `stream`):
  float* qbuf   = scratch;                 // [2304,512]
  float* kvbuf  = scratch + 1179648;       // [12,192,1024]
  float* obuf   = scratch + 3538944;       // [2304,512]
  float* kvpool = scratch;                 // [<=24,192,1024] = 4,718,592
  float* act    = scratch;                 // [2304,1408] = 3,244,032
  // readout aliases (msgbuf dead by then):
  float* robuf  = msgbuf;                  // [384,512]
  float* robuf2 = msgbuf + 196608;         // [384,512]
  float* ronorm = msgbuf + 393216;         // [384,512]

  auto gemm = [&](const float* A, const float* W, const float* bias, float* C,
                  int M, int N, int K, int ldc,
                  long long aStr, long long wStr, long long bStr, long long cStr,
                  int nb, int mode) {
    dim3 g((N + BN - 1) / BN, (M + BM - 1) / BM, nb);
    hipLaunchKernelGGL(gemm_f32split_kernel, g, dim3(256), 0, stream,
                       A, W, bias, C, M, N, K, ldc, aStr, wStr, bStr, cStr, mode);
  };

  // ---- FF weight prep (perm+pad) ----
  hipLaunchKernelGGL(ffk_perm_kernel, dim3((unsigned)((6ull * 2816 * 512 + 255) / 256)),
                     dim3(256), 0, stream, ff_kw, ff_kb, ffk_w, ffk_b);
  hipLaunchKernelGGL(ffv_pad_kernel, dim3((unsigned)((6ull * 512 * 1408 + 255) / 256)),
                     dim3(256), 0, stream, ff_vw, ffv_w);

  // ---- init: toks = broadcast(tokens); cache msg0 kv entries 0..5 ----
  {
    const int total = 6 * 2 * 192 * 512;
    hipLaunchKernelGGL(bcast_kernel, dim3((total + 255) / 256), dim3(256), 0, stream,
                       tokens, toks);
  }
  hipLaunchKernelGGL(rmsnorm_kernel, dim3(2304), dim3(256), 0, stream,
                     toks, res_nw, hbuf, 2304);
  gemm(hbuf, res_kvw, nullptr, kvpool, 384, 1024, 512, 1024,
       196608, 0, 0, 393216, 6, 0);
  hipLaunchKernelGGL(cache_fill_kernel, dim3(192, 12), dim3(128), 0, stream,
                     kvpool, res_knw, Kc, Vc, 0);

  for (int it = 0; it < 6; ++it) {
    // ---- block self-attention -> msgbuf[0] ----
    hipLaunchKernelGGL(rmsnorm_kernel, dim3(2304), dim3(256), 0, stream,
                       toks, attn_nw, hbuf, 384);
    gemm(hbuf, attn_qw, nullptr, qbuf, 384, 512, 512, 512,
         196608, 262144, 0, 196608, 6, 0);
    gemm(hbuf, attn_kvw, nullptr, kvbuf, 384, 1024, 512, 1024,
         196608, 524288, 0, 393216, 6, 0);
    hipLaunchKernelGGL(block_attn_kernel, dim3(48, 8, 12), dim3(256), 0, stream,
                       qbuf, kvbuf, obuf);
    gemm(obuf, attn_ow, nullptr, msgbuf, 384, 512, 512, 512,
         196608, 262144, 0, 196608, 6, 0);
    // ---- GEGLU FF (fused) -> msgbuf[1] ----
    hipLaunchKernelGGL(rmsnorm_kernel, dim3(2304), dim3(256), 0, stream,
                       toks, ff_nw, hbuf, 384);
    gemm(hbuf, ffk_w, ffk_b, act, 384, 2730, 512, 1408,
         196608, 1441792, 2816, 540672, 6, 1);       // clobbers qbuf/kvbuf (dead)
    gemm(act, ffv_w, ff_vb, msgbuf + 1179648, 384, 512, 1408, 512,
         540672, 720896, 512, 196608, 6, 0);
    // ---- cache kv for the two new messages ----
    hipLaunchKernelGGL(rmsnorm_kernel, dim3(4608), dim3(256), 0, stream,
                       msgbuf, res_nw, hbuf, 4608);
    gemm(hbuf, res_kvw, nullptr, kvpool, 384, 1024, 512, 1024,
         196608, 0, 0, 393216, 12, 0);               // clobbers act (dead)
    hipLaunchKernelGGL(cache_fill_kernel, dim3(192, 24), dim3(128), 0, stream,
                       kvpool, res_knw, Kc, Vc, (2 * it + 1) * 6);
    if (it == 5) break;
    // ---- pooled cross-attention over all cached entries -> new toks ----
    hipLaunchKernelGGL(rmsnorm_kernel, dim3(2304), dim3(256), 0, stream,
                       toks, res_nw, hbuf, 2304);
    gemm(hbuf, res_qw, nullptr, qbuf, 2304, 512, 512, 512,
         0, 0, 0, 0, 1, 0);                          // clobbers kvpool (dead)
    hipLaunchKernelGGL(pooled_attn_kernel, dim3(192, 8, 12), dim3(64), 0, stream,
                       qbuf, Kc, Vc, obuf, (3 + 2 * it) * 6, 0);
    gemm(obuf, res_ow, nullptr, toks, 2304, 512, 512, 512,
         0, 0, 0, 0, 1, 0);
  }

  // ---- readout ----
  hipLaunchKernelGGL(rmsnorm_kernel, dim3(1), dim3(256), 0, stream,
                     q_ro, res_nw, rqn, 1);
  gemm(rqn, res_qw, nullptr, rq, 1, 512, 512, 512, 0, 0, 0, 0, 1, 0);
  hipLaunchKernelGGL(pooled_attn_kernel, dim3(192, 8, 2), dim3(64), 0, stream,
                     rq, Kc, Vc, robuf, 78, 1);
  gemm(robuf, res_ow, nullptr, robuf2, 384, 512, 512, 512, 0, 0, 0, 0, 1, 0);
  hipLaunchKernelGGL(rmsnorm_kernel, dim3(384), dim3(256), 0, stream,
                     robuf2, ro_nw, ronorm, 384);
  gemm(ronorm, ro_w, nullptr, out, 384, 32000, 512, 32000, 0, 0, 0, 0, 1, 0);
}

// Round 7
// 3011.071 us; speedup vs baseline: 2.6083x; 1.1117x over previous
//
#include <hip/hip_runtime.h>
#include <hip/hip_bf16.h>
#include <math.h>

// ---------------------------------------------------------------------------
// DepthlessTransformer forward. Round 7: pooled attention amortizes K/V over
// the 6 queries sharing a context batch (ctx_b = j/6). Round-6 counters:
// pooled_attn 6x169us, FETCH 265MB/dispatch = 2.2x the 122MB K/V footprint
// (6 blocks re-fetched identical K/V tiles; working set >> L2). New layout:
// grid (192,8,2), one block stages K[M][64] once, 6 dots/softmaxes, one V
// sweep with 6 accumulators -> 6x less K/V traffic, 6x ILP.
// GEMMs + block_attn unchanged (round-6 proven, absmax 0.015625).
// D=512 H=8 DH=64 DI=512 L=6 NEX=6 FFI=1365 V=32000 B=2 N=192
// ---------------------------------------------------------------------------

#define EPSV 1.1920929e-07f
typedef __hip_bfloat16 bf16;
typedef __attribute__((ext_vector_type(4))) float f32x4;
typedef __attribute__((ext_vector_type(8))) short bf16x8;

__device__ inline void split8(const float* p, bf16x8& h8, bf16x8& l8) {
  f32x4 x0 = *(const f32x4*)(p);
  f32x4 x1 = *(const f32x4*)(p + 4);
#pragma unroll
  for (int i = 0; i < 4; ++i) {
    bf16 h0 = __float2bfloat16(x0[i]);
    bf16 l0 = __float2bfloat16(x0[i] - __bfloat162float(h0));
    h8[i] = __builtin_bit_cast(short, h0);
    l8[i] = __builtin_bit_cast(short, l0);
    bf16 h1 = __float2bfloat16(x1[i]);
    bf16 l1 = __float2bfloat16(x1[i] - __bfloat162float(h1));
    h8[i + 4] = __builtin_bit_cast(short, h1);
    l8[i + 4] = __builtin_bit_cast(short, l1);
  }
}

#define GLDS(src, dst) __builtin_amdgcn_global_load_lds( \
    (const __attribute__((address_space(1))) void*)(src), \
    (__attribute__((address_space(3))) void*)(dst), 16, 0, 0)

// ============== split-on-read GEMM: C = A * W^T (+bias), fp32 in/out =======
// A: [M,K] fp32 (batch stride aStr); W: [Nt,K] fp32 (batch stride wStr),
// Nt = N rounded up to 128 rows readable. C: [M,ldc] fp32. K % 32 == 0.
// mode 0: plain (+optional bias). mode 1: GEGLU fused -- W rows interleaved
// (2c=sim_c, 2c+1=gate_c), writes act[row][col>>1] = z_sim*gelu(z_gate).
#define BM 128
#define BN 128
#define BKG 32
__global__ __launch_bounds__(256) void gemm_f32split_kernel(
    const float* __restrict__ A, const float* __restrict__ W,
    const float* __restrict__ bias, float* __restrict__ C,
    int M, int N, int K, int ldc,
    long long aStr, long long wStr, long long bStr, long long cStr, int mode)
{
  int batch = blockIdx.z;
  A += (size_t)batch * aStr;
  W += (size_t)batch * wStr;
  C += (size_t)batch * cStr;
  if (bias) bias += (size_t)batch * bStr;
  int m0 = blockIdx.y * BM, n0 = blockIdx.x * BN;

  __shared__ float As[BM][BKG];   // 16 KB
  __shared__ float Ws[BN][BKG];   // 16 KB

  int t = threadIdx.x;
  int wave = t >> 6, lane = t & 63;
  int wr = wave >> 1, wc = wave & 1;       // wave's 64x64 quadrant
  int srow = lane >> 3;                    // staging: 8 rows per 1KB chunk
  int scol = (lane & 7) * 4;               // 4 floats (16B) per lane
  int fr = lane & 15, fq = lane >> 4;      // fragment row + k-group

  f32x4 acc[4][4] = {};

  for (int k0 = 0; k0 < K; k0 += BKG) {
#pragma unroll
    for (int c = 0; c < 4; ++c) {
      int rbase = wave * 32 + c * 8;       // 8-row chunk
      const float* gA = A + (size_t)(m0 + rbase + srow) * K + k0 + scol;
      GLDS(gA, &As[rbase][0]);
      const float* gW = W + (size_t)(n0 + rbase + srow) * K + k0 + scol;
      GLDS(gW, &Ws[rbase][0]);
    }
    __syncthreads();  // drains vmcnt before compute
    bf16x8 ah[4], al[4], wh[4], wl[4];
#pragma unroll
    for (int m = 0; m < 4; ++m)
      split8(&As[wr * 64 + m * 16 + fr][fq * 8], ah[m], al[m]);
#pragma unroll
    for (int n = 0; n < 4; ++n)
      split8(&Ws[wc * 64 + n * 16 + fr][fq * 8], wh[n], wl[n]);
#pragma unroll
    for (int m = 0; m < 4; ++m)
#pragma unroll
      for (int n = 0; n < 4; ++n) {
        acc[m][n] = __builtin_amdgcn_mfma_f32_16x16x32_bf16(ah[m], wh[n], acc[m][n], 0, 0, 0);
        acc[m][n] = __builtin_amdgcn_mfma_f32_16x16x32_bf16(al[m], wh[n], acc[m][n], 0, 0, 0);
        acc[m][n] = __builtin_amdgcn_mfma_f32_16x16x32_bf16(ah[m], wl[n], acc[m][n], 0, 0, 0);
      }
    __syncthreads();
  }

  if (mode == 0) {
#pragma unroll
    for (int m = 0; m < 4; ++m)
#pragma unroll
      for (int n = 0; n < 4; ++n) {
        int col = n0 + wc * 64 + n * 16 + fr;
        if (col >= N) continue;
        float bv = bias ? bias[col] : 0.f;
#pragma unroll
        for (int j = 0; j < 4; ++j) {
          int row = m0 + wr * 64 + m * 16 + fq * 4 + j;
          if (row < M) C[(size_t)row * ldc + col] = acc[m][n][j] + bv;
        }
      }
  } else {
    // GEGLU: even col = sim, odd col = gate (interleaved weight rows).
#pragma unroll
    for (int m = 0; m < 4; ++m)
#pragma unroll
      for (int n = 0; n < 4; ++n) {
        int col = n0 + wc * 64 + n * 16 + fr;
        float bv = bias[col];
#pragma unroll
        for (int j = 0; j < 4; ++j) {
          float z = acc[m][n][j] + bv;
          float zn = __shfl_xor(z, 1);   // partner: sim<->gate
          if (!(col & 1) && col < N) {
            float g = zn;
            float a = z * (0.5f * g * (1.f + erff(g * 0.70710678118654752f)));
            int row = m0 + wr * 64 + m * 16 + fq * 4 + j;
            if (row < M) C[(size_t)row * ldc + (col >> 1)] = a;
          }
        }
      }
  }
}

// ====== FF-keys weight perm+pad: [6,2730,512] -> [6,2816,512] interleaved ==
__global__ void ffk_perm_kernel(const float* __restrict__ kw,
                                const float* __restrict__ kb,
                                float* __restrict__ wout, float* __restrict__ bout)
{
  size_t idx = (size_t)blockIdx.x * 256 + threadIdx.x;
  const size_t per = 2816ull * 512;
  if (idx < 6 * per) {
    int b = (int)(idx / per);
    size_t r2 = idx % per;
    int r = (int)(r2 >> 9), k = (int)(r2 & 511);
    float v = 0.f;
    if (r < 2730) {
      int c = (r >> 1) + (r & 1) * 1365;
      v = kw[((size_t)b * 2730 + c) * 512 + k];
    }
    wout[idx] = v;
  }
  if (idx < 6 * 2816) {
    int b = (int)(idx / 2816), r = (int)(idx % 2816);
    float v = 0.f;
    if (r < 2730) {
      int c = (r >> 1) + (r & 1) * 1365;
      v = kb[(size_t)b * 2730 + c];
    }
    bout[idx] = v;
  }
}

// ====== FF-vals weight pad: [6,512,1365] -> [6,512,1408] (K zero-pad) ======
__global__ void ffv_pad_kernel(const float* __restrict__ vw, float* __restrict__ wout)
{
  size_t idx = (size_t)blockIdx.x * 256 + threadIdx.x;
  const size_t total = 6ull * 512 * 1408;
  if (idx >= total) return;
  int k = (int)(idx % 1408);
  size_t nr = idx / 1408;   // b*512 + n
  wout[idx] = (k < 1365) ? vw[nr * 1365 + k] : 0.f;
}

// ================= rmsnorm over dim 512 (fp32 -> fp32) =====================
__global__ __launch_bounds__(256) void rmsnorm_kernel(
    const float* __restrict__ x, const float* __restrict__ w,
    float* __restrict__ out, int rows_per_w)
{
  int r = blockIdx.x;
  int t = threadIdx.x;
  const float* xr = x + (size_t)r * 512;
  float a = xr[t], b = xr[t + 256];
  float ss = a * a + b * b;
  for (int off = 32; off; off >>= 1) ss += __shfl_xor(ss, off);
  __shared__ float wsum[4];
  if ((t & 63) == 0) wsum[t >> 6] = ss;
  __syncthreads();
  float tot = wsum[0] + wsum[1] + wsum[2] + wsum[3];
  float rs = rsqrtf(tot * (1.f / 512.f) + EPSV);
  const float* wr = w + (size_t)(r / rows_per_w) * 512;
  out[(size_t)r * 512 + t] = a * rs * wr[t];
  out[(size_t)r * 512 + t + 256] = b * rs * wr[t + 256];
}

// ================= broadcast tokens -> toks[L] =============================
__global__ void bcast_kernel(const float* __restrict__ tokens, float* __restrict__ toks)
{
  size_t idx = (size_t)blockIdx.x * 256 + threadIdx.x;
  const size_t total = (size_t)6 * 2 * 192 * 512;
  if (idx >= total) return;
  toks[idx] = tokens[idx % ((size_t)2 * 192 * 512)];
}

// ================= block self-attention, LDS-staged K ======================
// grid (48, 8, 12), 256 threads = 4 waves; wave w handles query i = bx*4+w.
__global__ __launch_bounds__(256) void block_attn_kernel(
    const float* __restrict__ q, const float* __restrict__ kv, float* __restrict__ o)
{
  int h = blockIdx.y, lb = blockIdx.z;
  int t = threadIdx.x;
  int wave = t >> 6, lane = t & 63;
  int i = blockIdx.x * 4 + wave;

  __shared__ float Ks[192][65];   // 49,920 B
  __shared__ float qs[4][64];
  __shared__ float ps[4][192];

  const float* kb = kv + (size_t)lb * 192 * 1024 + h * 64;
#pragma unroll
  for (int c = 0; c < 48; ++c) {
    int idx = c * 256 + t;
    int row = idx >> 6, col = idx & 63;
    Ks[row][col] = kb[(size_t)row * 1024 + col];
  }
  const float* qrow = q + ((size_t)(lb * 192 + i)) * 512 + h * 64;
  qs[wave][lane] = qrow[lane];
  __syncthreads();

  float s[3];
#pragma unroll
  for (int r = 0; r < 3; ++r) {
    int j = lane + r * 64;
    float acc = 0.f;
#pragma unroll 8
    for (int d = 0; d < 64; ++d) acc += qs[wave][d] * Ks[j][d];
    s[r] = acc;
  }
  float mx = fmaxf(fmaxf(s[0], s[1]), s[2]);
  for (int off = 32; off; off >>= 1) mx = fmaxf(mx, __shfl_xor(mx, off));
  float sum = 0.f;
#pragma unroll
  for (int r = 0; r < 3; ++r) { s[r] = expf(s[r] - mx); sum += s[r]; }
  for (int off = 32; off; off >>= 1) sum += __shfl_xor(sum, off);
  float inv = 1.f / sum;
#pragma unroll
  for (int r = 0; r < 3; ++r) ps[wave][lane + r * 64] = s[r] * inv;
  const float* vb = kb + 512;
  float acc = 0.f;
  for (int j = 0; j < 192; ++j) acc += ps[wave][j] * vb[(size_t)j * 1024 + lane];
  o[((size_t)(lb * 192 + i)) * 512 + h * 64 + lane] = acc;
}

// ================= pooled attention, K/V amortized over 6 queries ==========
// Kc/Vc: fp32 [78,2,192,512]. grid (192, 8, 2) for both modes.
// mode 0 (intermediate): z = ctx batch; handles queries j = z*6 + jj,
//   jj = 0..5 (q rows (z*6+jj)*192+n). K tile staged ONCE, V rows read once
//   and applied to 6 accumulators.
// mode 1 (readout): z = batch; single broadcast q row; o row = z*192+n.
__global__ __launch_bounds__(64) void pooled_attn_kernel(
    const float* __restrict__ q, const float* __restrict__ Kc,
    const float* __restrict__ Vc, float* __restrict__ o, int M, int mode)
{
  int n = blockIdx.x, h = blockIdx.y, z = blockIdx.z;
  int lane = threadIdx.x;
  int nq = mode ? 1 : 6;

  __shared__ float Ks[80][65];    // 20,800 B
  __shared__ float qs[6][64];
  __shared__ float p[6][128];

  // stage K entries: one coalesced 256B row per entry
  for (int m = 0; m < M; ++m)
    Ks[m][lane] = Kc[(((size_t)m * 2 + z) * 192 + n) * 512 + h * 64 + lane];
  for (int jj = 0; jj < nq; ++jj) {
    const float* qrow = mode ? (q + h * 64)
                             : (q + ((size_t)((z * 6 + jj) * 192 + n)) * 512 + h * 64);
    qs[jj][lane] = qrow[lane];
  }
  __syncthreads();

  // scores: lane handles keys m=lane and m=lane+64, for all nq queries
  float d0[6] = {}, d1[6] = {};
  int m1 = lane + 64;
#pragma unroll 4
  for (int d = 0; d < 64; ++d) {
    float k0 = Ks[lane][d];
    float k1 = Ks[m1 & 79][d];
#pragma unroll
    for (int jj = 0; jj < 6; ++jj) {
      float qv = qs[jj][d];
      d0[jj] += qv * k0;
      d1[jj] += qv * k1;
    }
  }
  float acc[6] = {};
#pragma unroll
  for (int jj = 0; jj < 6; ++jj) {
    if (jj >= nq) break;
    float s0 = (lane < M) ? d0[jj] : -1e30f;
    float s1 = (m1 < M) ? d1[jj] : -1e30f;
    float mx = fmaxf(s0, s1);
    for (int off = 32; off; off >>= 1) mx = fmaxf(mx, __shfl_xor(mx, off));
    float e0 = (lane < M) ? expf(s0 - mx) : 0.f;
    float e1 = (m1 < M) ? expf(s1 - mx) : 0.f;
    float sum = e0 + e1;
    for (int off = 32; off; off >>= 1) sum += __shfl_xor(sum, off);
    float inv = 1.f / sum;
    p[jj][lane] = e0 * inv;
    p[jj][m1] = e1 * inv;
  }
  __syncthreads();

  // PV: each V row read once (coalesced), applied to all nq accumulators
  for (int m = 0; m < M; ++m) {
    float v = Vc[(((size_t)m * 2 + z) * 192 + n) * 512 + h * 64 + lane];
#pragma unroll
    for (int jj = 0; jj < 6; ++jj) acc[jj] += p[jj][m] * v;
  }
#pragma unroll
  for (int jj = 0; jj < 6; ++jj) {
    if (jj >= nq) break;
    int orow = mode ? (z * 192 + n) : ((z * 6 + jj) * 192 + n);
    o[(size_t)orow * 512 + h * 64 + lane] = acc[jj];
  }
}

// ================= kv-cache fill (fp32, per-head key rmsnorm) ==============
__global__ __launch_bounds__(128) void cache_fill_kernel(
    const float* __restrict__ kvp, const float* __restrict__ knw,
    float* __restrict__ Kc, float* __restrict__ Vc, int base_e)
{
  int n = blockIdx.x;
  int t = blockIdx.y;
  int g = t >> 1, b = t & 1;
  int e = base_e + g;
  int lane = threadIdx.x;  // 128 lanes x 4 cols; 16 lanes per head
  const float* src = kvp + ((size_t)t * 192 + n) * 1024;
  float k4[4];
  float ss = 0.f;
#pragma unroll
  for (int u = 0; u < 4; ++u) { k4[u] = src[lane * 4 + u]; ss += k4[u] * k4[u]; }
  for (int off = 8; off; off >>= 1) ss += __shfl_xor(ss, off, 16);
  float rs = rsqrtf(ss * (1.f / 64.f) + EPSV);
  float* kd = Kc + (((size_t)e * 2 + b) * 192 + n) * 512;
  float* vd = Vc + (((size_t)e * 2 + b) * 192 + n) * 512;
#pragma unroll
  for (int u = 0; u < 4; ++u) {
    int c = lane * 4 + u;
    kd[c] = k4[u] * rs * knw[c & 63];
    vd[c] = src[512 + c];
  }
}

// ===========================================================================
extern "C" void kernel_launch(void* const* d_in, const int* in_sizes, int n_in,
                              void* d_out, int out_size, void* d_ws, size_t ws_size,
                              hipStream_t stream)
{
  const float* tokens   = (const float*)d_in[0];
  const float* attn_nw  = (const float*)d_in[1];
  const float* attn_qw  = (const float*)d_in[2];
  const float* attn_kvw = (const float*)d_in[3];
  const float* attn_ow  = (const float*)d_in[4];
  const float* ff_nw    = (const float*)d_in[5];
  const float* ff_kw    = (const float*)d_in[6];
  const float* ff_kb    = (const float*)d_in[7];
  const float* ff_vw    = (const float*)d_in[8];
  const float* ff_vb    = (const float*)d_in[9];
  const float* res_nw   = (const float*)d_in[10];
  const float* res_knw  = (const float*)d_in[11];
  const float* res_qw   = (const float*)d_in[12];
  const float* res_kvw  = (const float*)d_in[13];
  const float* res_ow   = (const float*)d_in[14];
  const float* q_ro     = (const float*)d_in[15];
  const float* ro_nw    = (const float*)d_in[16];
  const float* ro_w     = (const float*)d_in[17];
  float* out = (float*)d_out;

  // ---- workspace carve-up (54,281,728 floats = 217.1 MB) ----
  float* ws = (float*)d_ws;
  const size_t NEED = 54281728ull * 4ull;
  if (ws_size < NEED) return;
  float* ffk_w   = ws;  ws += 6ull * 2816 * 512;   // 8,650,752 (perm+pad fp32)
  float* ffk_b   = ws;  ws += 6ull * 2816;         // 16,896
  float* ffv_w   = ws;  ws += 6ull * 512 * 1408;   // 4,325,376 (K-pad fp32)
  float* toks    = ws;  ws += 1179648;             // [6,2,192,512]
  float* hbuf    = ws;  ws += 2359296;             // [<=4608,512]
  float* msgbuf  = ws;  ws += 2359296;             // [2,6,2,192,512]
  float* scratch = ws;  ws += 4718592;             // union region
  float* rqn     = ws;  ws += 512;
  float* rq      = ws;  ws += 512;
  float* Kc      = ws;  ws += 15335424;            // [78,2,192,512]
  float* Vc      = ws;  ws += 15335424;
  // scratch union (all uses strictly serialized on `stream`):
  float* qbuf   = scratch;                 // [2304,512]
  float* kvbuf  = scratch + 1179648;       // [12,192,1024]
  float* obuf   = scratch + 3538944;       // [2304,512]
  float* kvpool = scratch;                 // [<=24,192,1024] = 4,718,592
  float* act    = scratch;                 // [2304,1408] = 3,244,032
  // readout aliases (msgbuf dead by then):
  float* robuf  = msgbuf;                  // [384,512]
  float* robuf2 = msgbuf + 196608;         // [384,512]
  float* ronorm = msgbuf + 393216;         // [384,512]

  auto gemm = [&](const float* A, const float* W, const float* bias, float* C,
                  int M, int N, int K, int ldc,
                  long long aStr, long long wStr, long long bStr, long long cStr,
                  int nb, int mode) {
    dim3 g((N + BN - 1) / BN, (M + BM - 1) / BM, nb);
    hipLaunchKernelGGL(gemm_f32split_kernel, g, dim3(256), 0, stream,
                       A, W, bias, C, M, N, K, ldc, aStr, wStr, bStr, cStr, mode);
  };

  // ---- FF weight prep (perm+pad) ----
  hipLaunchKernelGGL(ffk_perm_kernel, dim3((unsigned)((6ull * 2816 * 512 + 255) / 256)),
                     dim3(256), 0, stream, ff_kw, ff_kb, ffk_w, ffk_b);
  hipLaunchKernelGGL(ffv_pad_kernel, dim3((unsigned)((6ull * 512 * 1408 + 255) / 256)),
                     dim3(256), 0, stream, ff_vw, ffv_w);

  // ---- init: toks = broadcast(tokens); cache msg0 kv entries 0..5 ----
  {
    const int total = 6 * 2 * 192 * 512;
    hipLaunchKernelGGL(bcast_kernel, dim3((total + 255) / 256), dim3(256), 0, stream,
                       tokens, toks);
  }
  hipLaunchKernelGGL(rmsnorm_kernel, dim3(2304), dim3(256), 0, stream,
                     toks, res_nw, hbuf, 2304);
  gemm(hbuf, res_kvw, nullptr, kvpool, 384, 1024, 512, 1024,
       196608, 0, 0, 393216, 6, 0);
  hipLaunchKernelGGL(cache_fill_kernel, dim3(192, 12), dim3(128), 0, stream,
                     kvpool, res_knw, Kc, Vc, 0);

  for (int it = 0; it < 6; ++it) {
    // ---- block self-attention -> msgbuf[0] ----
    hipLaunchKernelGGL(rmsnorm_kernel, dim3(2304), dim3(256), 0, stream,
                       toks, attn_nw, hbuf, 384);
    gemm(hbuf, attn_qw, nullptr, qbuf, 384, 512, 512, 512,
         196608, 262144, 0, 196608, 6, 0);
    gemm(hbuf, attn_kvw, nullptr, kvbuf, 384, 1024, 512, 1024,
         196608, 524288, 0, 393216, 6, 0);
    hipLaunchKernelGGL(block_attn_kernel, dim3(48, 8, 12), dim3(256), 0, stream,
                       qbuf, kvbuf, obuf);
    gemm(obuf, attn_ow, nullptr, msgbuf, 384, 512, 512, 512,
         196608, 262144, 0, 196608, 6, 0);
    // ---- GEGLU FF (fused) -> msgbuf[1] ----
    hipLaunchKernelGGL(rmsnorm_kernel, dim3(2304), dim3(256), 0, stream,
                       toks, ff_nw, hbuf, 384);
    gemm(hbuf, ffk_w, ffk_b, act, 384, 2730, 512, 1408,
         196608, 1441792, 2816, 540672, 6, 1);       // clobbers qbuf/kvbuf (dead)
    gemm(act, ffv_w, ff_vb, msgbuf + 1179648, 384, 512, 1408, 512,
         540672, 720896, 512, 196608, 6, 0);
    // ---- cache kv for the two new messages ----
    hipLaunchKernelGGL(rmsnorm_kernel, dim3(4608), dim3(256), 0, stream,
                       msgbuf, res_nw, hbuf, 4608);
    gemm(hbuf, res_kvw, nullptr, kvpool, 384, 1024, 512, 1024,
         196608, 0, 0, 393216, 12, 0);               // clobbers act (dead)
    hipLaunchKernelGGL(cache_fill_kernel, dim3(192, 24), dim3(128), 0, stream,
                       kvpool, res_knw, Kc, Vc, (2 * it + 1) * 6);
    if (it == 5) break;
    // ---- pooled cross-attention over all cached entries -> new toks ----
    hipLaunchKernelGGL(rmsnorm_kernel, dim3(2304), dim3(256), 0, stream,
                       toks, res_nw, hbuf, 2304);
    gemm(hbuf, res_qw, nullptr, qbuf, 2304, 512, 512, 512,
         0, 0, 0, 0, 1, 0);                          // clobbers kvpool (dead)
    hipLaunchKernelGGL(pooled_attn_kernel, dim3(192, 8, 2), dim3(64), 0, stream,
                       qbuf, Kc, Vc, obuf, (3 + 2 * it) * 6, 0);
    gemm(obuf, res_ow, nullptr, toks, 2304, 512, 512, 512,
         0, 0, 0, 0, 1, 0);
  }

  // ---- readout ----
  hipLaunchKernelGGL(rmsnorm_kernel, dim3(1), dim3(256), 0, stream,
                     q_ro, res_nw, rqn, 1);
  gemm(rqn, res_qw, nullptr, rq, 1, 512, 512, 512, 0, 0, 0, 0, 1, 0);
  hipLaunchKernelGGL(pooled_attn_kernel, dim3(192, 8, 2), dim3(64), 0, stream,
                     rq, Kc, Vc, robuf, 78, 1);
  gemm(robuf, res_ow, nullptr, robuf2, 384, 512, 512, 512, 0, 0, 0, 0, 1, 0);
  hipLaunchKernelGGL(rmsnorm_kernel, dim3(384), dim3(256), 0, stream,
                     robuf2, ro_nw, ronorm, 384);
  gemm(ronorm, ro_w, nullptr, out, 384, 32000, 512, 32000, 0, 0, 0, 0, 1, 0);
}